// Round 9
// baseline (868.440 us; speedup 1.0000x reference)
//
#include <hip/hip_runtime.h>
#include <hip/hip_bf16.h>

#define F 128
#define F3 384
#define NRBF 20
#define NITER 3
#define KP 24   // padded filter K: 0..19 phi*fc, 20 fc (bias slot), 21..23 zero

typedef __hip_bfloat16 bf16;
typedef __bf16 bfrag __attribute__((ext_vector_type(8)));
typedef float f32x4 __attribute__((ext_vector_type(4)));

__device__ __forceinline__ float b2f(bf16 v) { return __bfloat162float(v); }
__device__ __forceinline__ bf16 f2b(float v) { return __float2bfloat16(v); }
__device__ __forceinline__ bfrag ldb(const bf16* p) { return *(const bfrag*)p; }
__device__ __forceinline__ bfrag ldsb(const __bf16* p) { return *(const bfrag*)p; }
__device__ __forceinline__ bfrag cvtf(const float* p) {
    bfrag r;
#pragma unroll
    for (int j = 0; j < 8; ++j) r[j] = (__bf16)p[j];
    return r;
}

// ---------------- dtype detection: bf16 (flag=0) vs f32 (flag=1) ----------------
__global__ void detect_kernel(const unsigned short* __restrict__ raw, int n_u16,
                              int* __restrict__ flag) {
    int i = blockIdx.x * blockDim.x + threadIdx.x;
    int bad = 0;
    for (int k = i; k < n_u16; k += blockDim.x * gridDim.x) {
        unsigned e = (raw[k] >> 7) & 0xFFu;
        if (e >= 140u) bad = 1;
    }
    if (bad) atomicOr(flag, 1);
}

// ---------------- fused param convert: 13 arrays in one launch ----------------
struct CvtArgs {
    const void* src[13];
    float* dst[13];
    int end[14];
};
__global__ void cvt_all_kernel(CvtArgs a, const int* __restrict__ flag, int total) {
    int idx = blockIdx.x * blockDim.x + threadIdx.x;
    if (idx >= total) return;
    int s = 0;
    while (idx >= a.end[s + 1]) ++s;
    int local = idx - a.end[s];
    float v = (*flag) ? ((const float*)a.src[s])[local]
                      : b2f(((const bf16*)a.src[s])[local]);
    a.dst[s][local] = v;
}

// ---------------- fused transpose: 5 weight tensors, f32[NITER][K][Nn]->bf16[NITER][Nn][K] ----
struct TpArgs {
    const float* src[5];
    bf16* dst[5];
    int K[5];
    int Nn[5];
    int end[6];
};
__global__ void tpose_all_kernel(TpArgs a, int total) {
    int idx = blockIdx.x * blockDim.x + threadIdx.x;
    if (idx >= total) return;
    int s = 0;
    while (idx >= a.end[s + 1]) ++s;
    int local = idx - a.end[s];
    int K = a.K[s], Nn = a.Nn[s], slice = K * Nn;
    int t = local / slice, j = local - t * slice;
    int n = j / K, k = j - n * K;
    a.dst[s][local] = f2b(a.src[s][t * slice + k * Nn + n]);
}

// ---------------- fWTf: f32 [NITER][384][24], k=0..19 fW, k=20 fb, rest 0 ----------------
__global__ void fwt_kernel(const float* __restrict__ fW, const float* __restrict__ fb,
                           float* __restrict__ dst, int total) {
    int idx = blockIdx.x * blockDim.x + threadIdx.x;
    if (idx >= total) return;
    int k = idx % KP, rest = idx / KP;
    int n = rest % F3, t = rest / F3;
    float v = (k < NRBF) ? fW[k * (F3 * NITER) + t * F3 + n]
                         : (k == NRBF ? fb[t * F3 + n] : 0.0f);
    dst[idx] = v;
}

// ---------------- geometry -> CSR-slot-ordered edge data ----------------
// dir2[l] = {dx, dy, dz, bitcast(j)}; phifc2 stored BF16 (halves the phi stream)
__global__ void geom_kernel(const float* __restrict__ pos, const int* __restrict__ ii,
                            const int* __restrict__ jj, const int* __restrict__ rank,
                            bf16* __restrict__ phifc2, float* __restrict__ dir2, int E) {
    int e = blockIdx.x * blockDim.x + threadIdx.x;
    if (e >= E) return;
    int i = ii[e], j = jj[e], l = rank[e];
    float r[3];
#pragma unroll
    for (int d = 0; d < 3; ++d) {
        float v = pos[j * 3 + d] - pos[i * 3 + d];
        if (fabsf(v) < 1e-6f) v = 1e-6f;
        r[d] = v;
    }
    float dd = sqrtf(r[0] * r[0] + r[1] * r[1] + r[2] * r[2]);
    float inv = 1.0f / dd;
#pragma unroll
    for (int d = 0; d < 3; ++d) dir2[(size_t)l * 4 + d] = r[d] * inv;
    dir2[(size_t)l * 4 + 3] = __int_as_float(j);
    const float CUT = 5.0f;
    const float PI = 3.14159265358979323846f;
    float fc = (dd < CUT) ? 0.5f * (cosf(PI * dd / CUT) + 1.0f) : 0.0f;
    const float width = CUT / (NRBF - 1);
    const float coeff = -0.5f / (width * width);
    bf16* pr = phifc2 + (size_t)l * KP;
#pragma unroll
    for (int k = 0; k < NRBF; ++k) {
        float diff = dd - (float)k * width;
        pr[k] = f2b(expf(coeff * diff * diff) * fc);
    }
    pr[NRBF] = f2b(fc);
    pr[NRBF + 1] = f2b(0.0f);
    pr[NRBF + 2] = f2b(0.0f);
    pr[NRBF + 3] = f2b(0.0f);
}

// ---------------- initial q from embedding ----------------
__global__ void embed_kernel(const int* __restrict__ z, const float* __restrict__ emb,
                             float* __restrict__ q, int N) {
    int idx = blockIdx.x * blockDim.x + threadIdx.x;
    if (idx >= N * F) return;
    int n = idx >> 7, f = idx & 127;
    q[idx] = emb[z[n] * F + f];
}

// ---------------- CSR build ----------------
__global__ void count_kernel(const int* __restrict__ ii, int* __restrict__ counts, int E) {
    int e = blockIdx.x * blockDim.x + threadIdx.x;
    if (e < E) atomicAdd(&counts[ii[e]], 1);
}

__global__ void scan_kernel(const int* __restrict__ counts, int* __restrict__ offs, int N) {
    __shared__ int cum[1024];
    int t = threadIdx.x;
    int chunk = (N + 1023) >> 10;
    int b = t * chunk;
    int e = b + chunk; if (e > N) e = N;
    int s = 0;
    for (int a = b; a < e; ++a) s += counts[a];
    cum[t] = s;
    __syncthreads();
    for (int o = 1; o < 1024; o <<= 1) {
        int u = (t >= o) ? cum[t - o] : 0;
        __syncthreads();
        cum[t] += u;
        __syncthreads();
    }
    int run = cum[t] - s;
    for (int a = b; a < e; ++a) { offs[a] = run; run += counts[a]; }
    if (t == 1023) offs[N] = cum[1023];
}

__global__ void fill_kernel(const int* __restrict__ ii, const int* __restrict__ offs,
                            int* __restrict__ cursor, int* __restrict__ rank, int E) {
    int e = blockIdx.x * blockDim.x + threadIdx.x;
    if (e >= E) return;
    int i = ii[e];
    int p = atomicAdd(&cursor[i], 1);
    rank[e] = offs[i] + p;
}

// ---------------- atom_x via MFMA: X = silu(Q@W1+b1)@W2+b2, 32 atoms/block ----------------
// The empirically-proven fast shape (~15us, ~2.1 TB/s effective): 2 phases, 8.7KB LDS.
__global__ __launch_bounds__(256) void atom_x_mfma(
    const float* __restrict__ q, const bf16* __restrict__ W1T, const float* __restrict__ b1,
    const bf16* __restrict__ W2T, const float* __restrict__ b2, bf16* __restrict__ x, int N) {
    __shared__ __bf16 H[32][136];
    int tid = threadIdx.x;
    int w = tid >> 6, l = tid & 63;
    int lm = l & 15, q4 = l >> 4;
    int i0 = blockIdx.x * 32;
    f32x4 acc[2][2] = {};
    int r0 = min(i0 + lm, N - 1);
    int r1 = min(i0 + 16 + lm, N - 1);
    for (int kt = 0; kt < 4; ++kt) {
        int ko = kt * 32 + q4 * 8;
        bfrag a0 = cvtf(q + (size_t)r0 * F + ko);
        bfrag a1 = cvtf(q + (size_t)r1 * F + ko);
        bfrag b0 = ldb(W1T + (size_t)(w * 32 + lm) * F + ko);
        bfrag b1f = ldb(W1T + (size_t)(w * 32 + 16 + lm) * F + ko);
        acc[0][0] = __builtin_amdgcn_mfma_f32_16x16x32_bf16(a0, b0, acc[0][0], 0, 0, 0);
        acc[1][0] = __builtin_amdgcn_mfma_f32_16x16x32_bf16(a1, b0, acc[1][0], 0, 0, 0);
        acc[0][1] = __builtin_amdgcn_mfma_f32_16x16x32_bf16(a0, b1f, acc[0][1], 0, 0, 0);
        acc[1][1] = __builtin_amdgcn_mfma_f32_16x16x32_bf16(a1, b1f, acc[1][1], 0, 0, 0);
    }
#pragma unroll
    for (int nt = 0; nt < 2; ++nt) {
        int col = w * 32 + nt * 16 + lm;
        float bb = b1[col];
#pragma unroll
        for (int mt = 0; mt < 2; ++mt)
#pragma unroll
            for (int r = 0; r < 4; ++r) {
                float v = acc[mt][nt][r] + bb;
                H[mt * 16 + q4 * 4 + r][col] = (__bf16)(v / (1.0f + expf(-v)));
            }
    }
    __syncthreads();
#pragma unroll
    for (int j = 0; j < 6; ++j) {
        int n0 = w * 96 + j * 16;
        f32x4 c0 = {}, c1 = {};
        const bf16* bp = W2T + (size_t)(n0 + lm) * F;
        for (int kt = 0; kt < 4; ++kt) {
            int ko = kt * 32 + q4 * 8;
            bfrag a0 = ldsb(&H[lm][ko]);
            bfrag a1 = ldsb(&H[16 + lm][ko]);
            bfrag bf = ldb(bp + ko);
            c0 = __builtin_amdgcn_mfma_f32_16x16x32_bf16(a0, bf, c0, 0, 0, 0);
            c1 = __builtin_amdgcn_mfma_f32_16x16x32_bf16(a1, bf, c1, 0, 0, 0);
        }
        int col = n0 + lm;
        float bb = b2[col];
#pragma unroll
        for (int r = 0; r < 4; ++r) {
            int row0 = i0 + q4 * 4 + r;
            int row1 = row0 + 16;
            if (row0 < N) x[(size_t)row0 * F3 + col] = f2b(c0[r] + bb);
            if (row1 < N) x[(size_t)row1 * F3 + col] = f2b(c1[r] + bb);
        }
    }
}

// ---------------- edge gather v5: delta outputs, bf16 phi + bf16 dq ----------------
// Model (6 data points): dur ~= (FETCH+WRITE) / ~1.7 TB/s.
template<int T0>
__global__ __launch_bounds__(128, 2) void edge_gather_d(
    const bf16* __restrict__ mu_in, const bf16* __restrict__ x,
    const bf16* __restrict__ phifc2, const float* __restrict__ dir2,
    const float* __restrict__ fWTf, const int* __restrict__ offs,
    bf16* __restrict__ dq, bf16* __restrict__ dmu, int N) {
    int i = blockIdx.x;
    int f = threadIdx.x;
    float w0[21], w1[21], w2[21];
    {
        const f32x4* p0 = (const f32x4*)(fWTf + (size_t)f * KP);
        const f32x4* p1 = (const f32x4*)(fWTf + (size_t)(f + 128) * KP);
#pragma unroll
        for (int k = 0; k < 6; ++k) {
            f32x4 t0 = p0[k], t1 = p1[k];
#pragma unroll
            for (int r = 0; r < 4; ++r) {
                int kk = k * 4 + r;
                if (kk < 21) { w0[kk] = t0[r]; w1[kk] = t1[r]; }
            }
        }
        if constexpr (!T0) {
            const f32x4* p2 = (const f32x4*)(fWTf + (size_t)(f + 256) * KP);
#pragma unroll
            for (int k = 0; k < 6; ++k) {
                f32x4 t2 = p2[k];
#pragma unroll
                for (int r = 0; r < 4; ++r) {
                    int kk = k * 4 + r;
                    if (kk < 21) w2[kk] = t2[r];
                }
            }
        }
    }
    // pin: value becomes opaque to the compiler -> cannot rematerialize the load
#pragma unroll
    for (int k = 0; k < 21; ++k) {
        asm volatile("" : "+v"(w0[k]), "+v"(w1[k]));
        if constexpr (!T0) asm volatile("" : "+v"(w2[k]));
    }
    int beg = offs[i], end = offs[i + 1];
    float accq = 0.0f, am0 = 0.0f, am1 = 0.0f, am2 = 0.0f;
    for (int l = beg; l < end; ++l) {
        const bfrag* pb = (const bfrag*)(phifc2 + (size_t)l * KP);
        bfrag p0 = __builtin_nontemporal_load(pb);
        bfrag p1 = __builtin_nontemporal_load(pb + 1);
        bfrag p2 = __builtin_nontemporal_load(pb + 2);
        float ph[21];
#pragma unroll
        for (int k = 0; k < 8; ++k) ph[k] = (float)p0[k];
#pragma unroll
        for (int k = 0; k < 8; ++k) ph[8 + k] = (float)p1[k];
#pragma unroll
        for (int k = 0; k < 5; ++k) ph[16 + k] = (float)p2[k];
        float fl0 = 0.0f, fl1 = 0.0f, fl2 = 0.0f;
#pragma unroll
        for (int k = 0; k < 21; ++k) {
            fl0 += ph[k] * w0[k];
            fl1 += ph[k] * w1[k];
            if constexpr (!T0) fl2 += ph[k] * w2[k];
        }
        f32x4 dv = __builtin_nontemporal_load((const f32x4*)(dir2 + (size_t)l * 4));
        int j = __float_as_int(dv[3]);
        const bf16* xj = x + (size_t)j * F3;
        float dqv = fl0 * b2f(xj[f]);
        float dR = fl1 * b2f(xj[f + 128]);
        accq += dqv;
        if constexpr (!T0) {
            float dM = fl2 * b2f(xj[f + 256]);
            const bf16* muj = mu_in + (size_t)j * F3;
            am0 += dR * dv[0] + dM * b2f(muj[f]);
            am1 += dR * dv[1] + dM * b2f(muj[f + 128]);
            am2 += dR * dv[2] + dM * b2f(muj[f + 256]);
        } else {
            am0 += dR * dv[0];
            am1 += dR * dv[1];
            am2 += dR * dv[2];
        }
    }
    dq[(size_t)i * F + f] = f2b(accq);
    size_t mb = (size_t)i * F3 + f;
    dmu[mb]       = f2b(am0);
    dmu[mb + 128] = f2b(am1);
    dmu[mb + 256] = f2b(am2);
}

// ---------------- mix8: full mixing, 8 atoms/block (fused-traffic, split-shape) ----------------
// R9: R8 showed every kernel runs at ~1.6-2.1 TB/s effective traffic. R7's fused mix
// had minimal traffic (90 MB/iter) but 0.8 TB/s (2.7 blocks/CU, 7 barriers); R8's
// split had 2.1 TB/s but 237 MB/iter. mix8 = fused traffic at split shape: 8 atoms/
// block (grid 3125), 4 barriers, 29.5KB LDS (Y aliases VV) -> 5 blocks/CU.
template<int T0, int OUT>
__global__ __launch_bounds__(256) void mix8(
    float* __restrict__ q, const bf16* __restrict__ dqb,
    const bf16* __restrict__ mu_in, const bf16* __restrict__ dmu,
    bf16* __restrict__ mu_out,
    const bf16* __restrict__ WmixT, const bf16* __restrict__ W1T, const float* __restrict__ b1,
    const bf16* __restrict__ W2T, const float* __restrict__ b2,
    void* __restrict__ outp, const int* __restrict__ flag, int N) {
    // LDS layout (29568 B):
    //   [0    ,  6336): WW [24][132] bf16   persistent (W-half of mu_mix)
    //   [6336 , 12672): VV [24][132] bf16 (ph1->CT)  |  Y [8][392] bf16 (C->D)  [aliased]
    //   [12672, 21120): CT [16][264] bf16   (CT->B; rows 8..15 zero pad)
    //   [21120, 25472): HM [16][136] bf16   (B->C)
    //   [25472, 29568): SS [8][128]  f32    persistent (s = sum V*W)
    __shared__ __align__(16) char smem[29568];
    __bf16 (*WW)[132] = (__bf16(*)[132])(smem);
    __bf16 (*VV)[132] = (__bf16(*)[132])(smem + 6336);
    __bf16 (*Y)[392]  = (__bf16(*)[392])(smem + 6336);
    __bf16 (*CT)[264] = (__bf16(*)[264])(smem + 12672);
    __bf16 (*HM)[136] = (__bf16(*)[136])(smem + 21120);
    float  (*SS)[128] = (float(*)[128])(smem + 25472);
    int tid = threadIdx.x;
    int w = tid >> 6, l = tid & 63;
    int lm = l & 15, q4 = l >> 4;
    int i0 = blockIdx.x * 8;
    int rowsM = N * 3;
    // Phase 1: Wmix GEMM (24 real mu rows x 256 cols)
    {
        f32x4 acc[2][4] = {};
        int mr[2];
        mr[0] = min(i0 * 3 + lm, rowsM - 1);
        mr[1] = min(i0 * 3 + 16 + lm, rowsM - 1);
        for (int kt = 0; kt < 4; ++kt) {
            int ko = kt * 32 + q4 * 8;
            bfrag a[2], b[4];
#pragma unroll
            for (int mt = 0; mt < 2; ++mt) {
                bfrag d = ldb(dmu + (size_t)mr[mt] * F + ko);
                if constexpr (T0) {
                    a[mt] = d;
                } else {
                    bfrag u = ldb(mu_in + (size_t)mr[mt] * F + ko);
#pragma unroll
                    for (int jj = 0; jj < 8; ++jj)
                        a[mt][jj] = (__bf16)((float)u[jj] + (float)d[jj]);
                }
            }
#pragma unroll
            for (int nt = 0; nt < 4; ++nt)
                b[nt] = ldb(WmixT + (size_t)(w * 64 + nt * 16 + lm) * F + ko);
#pragma unroll
            for (int mt = 0; mt < 2; ++mt)
#pragma unroll
                for (int nt = 0; nt < 4; ++nt)
                    acc[mt][nt] = __builtin_amdgcn_mfma_f32_16x16x32_bf16(a[mt], b[nt], acc[mt][nt], 0, 0, 0);
        }
#pragma unroll
        for (int mt = 0; mt < 2; ++mt)
#pragma unroll
            for (int nt = 0; nt < 4; ++nt) {
                int col = w * 64 + nt * 16 + lm;   // uniform per (w,nt): col<128 iff w<2
#pragma unroll
                for (int r = 0; r < 4; ++r) {
                    int row = mt * 16 + q4 * 4 + r;
                    if (row < 24) {
                        if (col < 128) VV[row][col] = (__bf16)acc[mt][nt][r];
                        else           WW[row][col - 128] = (__bf16)acc[mt][nt][r];
                    }
                }
            }
    }
    __syncthreads();
    // CT/SS build (CT rows 8..15 zeroed for the MFMA pad)
    for (int idx = tid; idx < 16 * F; idx += 256) {
        int a = idx >> 7, f = idx & 127;
        if (a < 8) {
            int i = min(i0 + a, N - 1);
            float v0 = (float)VV[a * 3 + 0][f], ww0 = (float)WW[a * 3 + 0][f];
            float v1 = (float)VV[a * 3 + 1][f], ww1 = (float)WW[a * 3 + 1][f];
            float v2 = (float)VV[a * 3 + 2][f], ww2 = (float)WW[a * 3 + 2][f];
            SS[a][f] = v0 * ww0 + v1 * ww1 + v2 * ww2;
            size_t qb = (size_t)i * F + f;
            CT[a][f] = (__bf16)(q[qb] + b2f(dqb[qb]));
            CT[a][F + f] = (__bf16)sqrtf(v0 * v0 + v1 * v1 + v2 * v2 + 1e-8f);
        } else {
            CT[a][f] = (__bf16)0.0f;
            CT[a][F + f] = (__bf16)0.0f;
        }
    }
    __syncthreads();   // VV dead from here; Y may reuse its storage
    // B: HM = silu(CT @ W1 + b1), K=256
    {
        f32x4 c[2] = {};
        for (int kt = 0; kt < 8; ++kt) {
            int ko = kt * 32 + q4 * 8;
            bfrag a = ldsb(&CT[lm][ko]);
#pragma unroll
            for (int nt = 0; nt < 2; ++nt) {
                bfrag b = ldb(W1T + (size_t)(w * 32 + nt * 16 + lm) * 256 + ko);
                c[nt] = __builtin_amdgcn_mfma_f32_16x16x32_bf16(a, b, c[nt], 0, 0, 0);
            }
        }
#pragma unroll
        for (int nt = 0; nt < 2; ++nt) {
            int col = w * 32 + nt * 16 + lm;
            float bb = b1[col];
#pragma unroll
            for (int r = 0; r < 4; ++r) {
                float v = c[nt][r] + bb;
                HM[q4 * 4 + r][col] = (__bf16)(v / (1.0f + expf(-v)));
            }
        }
    }
    __syncthreads();
    // C: Y = HM @ W2 + b2 (keep rows < 8)
#pragma unroll
    for (int j = 0; j < 6; ++j) {
        int n0 = w * 96 + j * 16;
        f32x4 c = {};
        const bf16* bp = W2T + (size_t)(n0 + lm) * F;
        for (int kt = 0; kt < 4; ++kt) {
            int ko = kt * 32 + q4 * 8;
            bfrag a = ldsb(&HM[lm][ko]);
            bfrag b = ldb(bp + ko);
            c = __builtin_amdgcn_mfma_f32_16x16x32_bf16(a, b, c, 0, 0, 0);
        }
        int col = n0 + lm;
        float bb = b2[col];
#pragma unroll
        for (int r = 0; r < 4; ++r) {
            int row = q4 * 4 + r;
            if (row < 8) Y[row][col] = (__bf16)(c[r] + bb);
        }
    }
    __syncthreads();
    // D: elementwise final update
    int nq = N * F;
    for (int idx = tid; idx < 8 * F; idx += 256) {
        int a = idx >> 7, f = idx & 127;
        int i = i0 + a;
        if (i >= N) continue;
        size_t qb = (size_t)i * F + f;
        size_t mb = (size_t)i * F3 + f;
        float yq = (float)Y[a][f], ym = (float)Y[a][F + f], ys = (float)Y[a][2 * F + f];
        float s = SS[a][f];
        float W0 = (float)WW[a * 3 + 0][f];
        float W1v = (float)WW[a * 3 + 1][f];
        float W2v = (float)WW[a * 3 + 2][f];
        float qv = q[qb] + b2f(dqb[qb]) + yq + ys * s;
        float m0 = b2f(dmu[mb]);
        float m1 = b2f(dmu[mb + 128]);
        float m2 = b2f(dmu[mb + 256]);
        if constexpr (!T0) {
            m0 += b2f(mu_in[mb]);
            m1 += b2f(mu_in[mb + 128]);
            m2 += b2f(mu_in[mb + 256]);
        }
        m0 += ym * W0;
        m1 += ym * W1v;
        m2 += ym * W2v;
        if constexpr (OUT) {
            if (*flag) {
                float* of = (float*)outp;
                of[qb] = qv;
                of[nq + mb] = m0;
                of[nq + mb + 128] = m1;
                of[nq + mb + 256] = m2;
            } else {
                bf16* ob = (bf16*)outp;
                ob[qb] = f2b(qv);
                ob[nq + mb] = f2b(m0);
                ob[nq + mb + 128] = f2b(m1);
                ob[nq + mb + 256] = f2b(m2);
            }
        } else {
            q[qb] = qv;
            mu_out[mb]       = f2b(m0);
            mu_out[mb + 128] = f2b(m1);
            mu_out[mb + 256] = f2b(m2);
        }
    }
}

extern "C" void kernel_launch(void* const* d_in, const int* in_sizes, int n_in,
                              void* d_out, int out_size, void* d_ws, size_t ws_size,
                              hipStream_t stream) {
    const int* z = (const int*)d_in[0];
    const int* idx_i = (const int*)d_in[2];
    const int* idx_j = (const int*)d_in[3];

    int N = in_sizes[0];
    int E = in_sizes[2];

    char* base = (char*)d_ws;
    size_t off = 0;
    auto alloc = [&](size_t bytes) -> void* {
        void* p = base + off;
        off += (bytes + 255) & ~(size_t)255;
        return p;
    };

    int* flag = (int*)alloc(4);
    float* pos_f = (float*)alloc((size_t)in_sizes[1] * 4);
    float* emb_f = (float*)alloc((size_t)in_sizes[4] * 4);
    float* fW_f = (float*)alloc((size_t)in_sizes[5] * 4);
    float* fb_f = (float*)alloc((size_t)in_sizes[6] * 4);
    float* iW1_f = (float*)alloc((size_t)in_sizes[7] * 4);
    float* ib1_f = (float*)alloc((size_t)in_sizes[8] * 4);
    float* iW2_f = (float*)alloc((size_t)in_sizes[9] * 4);
    float* ib2_f = (float*)alloc((size_t)in_sizes[10] * 4);
    float* mWmix_f = (float*)alloc((size_t)in_sizes[11] * 4);
    float* mW1_f = (float*)alloc((size_t)in_sizes[12] * 4);
    float* mb1_f = (float*)alloc((size_t)in_sizes[13] * 4);
    float* mW2_f = (float*)alloc((size_t)in_sizes[14] * 4);
    float* mb2_f = (float*)alloc((size_t)in_sizes[15] * 4);
    bf16* iW1T = (bf16*)alloc((size_t)NITER * F * F * 2);
    bf16* iW2T = (bf16*)alloc((size_t)NITER * F3 * F * 2);
    bf16* mWmixT = (bf16*)alloc((size_t)NITER * 2 * F * F * 2);
    bf16* mW1T = (bf16*)alloc((size_t)NITER * F * 2 * F * 2);
    bf16* mW2T = (bf16*)alloc((size_t)NITER * F3 * F * 2);
    float* fWTf = (float*)alloc((size_t)NITER * F3 * KP * 4);
    float* q = (float*)alloc((size_t)N * F * 4);
    bf16* dqb = (bf16*)alloc((size_t)N * F * 2);
    bf16* mua = (bf16*)alloc((size_t)N * F3 * 2);
    bf16* mub = (bf16*)alloc((size_t)N * F3 * 2);
    bf16* dmub = (bf16*)alloc((size_t)N * F3 * 2);
    bf16* xbuf = (bf16*)alloc((size_t)N * F3 * 2);
    bf16* phifc2 = (bf16*)alloc((size_t)(E + 16) * KP * 2);
    float* dir2 = (float*)alloc((size_t)(E + 16) * 4 * 4);
    int* rank = (int*)alloc((size_t)E * 4);
    int* counts = (int*)alloc((size_t)N * 4);
    int* offs = (int*)alloc((size_t)(N + 1) * 4);

    hipMemsetAsync(flag, 0, 4, stream);
    detect_kernel<<<64, 256, 0, stream>>>((const unsigned short*)d_in[1], in_sizes[1], flag);

    {
        CvtArgs a;
        const int srcIdx[13] = {1, 4, 5, 6, 7, 8, 9, 10, 11, 12, 13, 14, 15};
        float* dsts[13] = {pos_f, emb_f, fW_f, fb_f, iW1_f, ib1_f, iW2_f, ib2_f,
                           mWmix_f, mW1_f, mb1_f, mW2_f, mb2_f};
        int cum = 0;
        a.end[0] = 0;
        for (int s = 0; s < 13; ++s) {
            a.src[s] = d_in[srcIdx[s]];
            a.dst[s] = dsts[s];
            cum += in_sizes[srcIdx[s]];
            a.end[s + 1] = cum;
        }
        cvt_all_kernel<<<(cum + 255) / 256, 256, 0, stream>>>(a, flag, cum);
    }

    {
        TpArgs a;
        const float* srcs[5] = {iW1_f, iW2_f, mWmix_f, mW1_f, mW2_f};
        bf16* dsts[5] = {iW1T, iW2T, mWmixT, mW1T, mW2T};
        int Ks[5] = {F, F, F, 2 * F, F};
        int Nns[5] = {F, F3, 2 * F, F, F3};
        int cum = 0;
        a.end[0] = 0;
        for (int s = 0; s < 5; ++s) {
            a.src[s] = srcs[s];
            a.dst[s] = dsts[s];
            a.K[s] = Ks[s];
            a.Nn[s] = Nns[s];
            cum += NITER * Ks[s] * Nns[s];
            a.end[s + 1] = cum;
        }
        tpose_all_kernel<<<(cum + 255) / 256, 256, 0, stream>>>(a, cum);
    }
    {
        int total = NITER * F3 * KP;
        fwt_kernel<<<(total + 255) / 256, 256, 0, stream>>>(fW_f, fb_f, fWTf, total);
    }

    // CSR build (rank needed by geom)
    hipMemsetAsync(counts, 0, (size_t)N * 4, stream);
    count_kernel<<<(E + 255) / 256, 256, 0, stream>>>(idx_i, counts, E);
    scan_kernel<<<1, 1024, 0, stream>>>(counts, offs, N);
    hipMemsetAsync(counts, 0, (size_t)N * 4, stream);
    fill_kernel<<<(E + 255) / 256, 256, 0, stream>>>(idx_i, offs, counts, rank, E);

    geom_kernel<<<(E + 255) / 256, 256, 0, stream>>>(pos_f, idx_i, idx_j, rank,
                                                     phifc2, dir2, E);
    embed_kernel<<<(N * F + 255) / 256, 256, 0, stream>>>(z, emb_f, q, N);
    // mua never read before first full write (t=0 path uses deltas only)

    int grid8 = (N + 7) / 8;
    int grid32 = (N + 31) / 32;
    bf16* muin = mua;
    bf16* muout = mub;
    // x for t=0 from initial q
    atom_x_mfma<<<grid32, 256, 0, stream>>>(q, iW1T, ib1_f, iW2T, ib2_f, xbuf, N);
    // ---- t = 0 ----
    edge_gather_d<1><<<N, 128, 0, stream>>>(muin, xbuf, phifc2, dir2,
                                            fWTf, offs, dqb, dmub, N);
    mix8<1, 0><<<grid8, 256, 0, stream>>>(q, dqb, muin, dmub, muout,
                                          mWmixT, mW1T, mb1_f, mW2T, mb2_f,
                                          nullptr, flag, N);
    atom_x_mfma<<<grid32, 256, 0, stream>>>(q, iW1T + (size_t)1 * F * F, ib1_f + 1 * F,
                                            iW2T + (size_t)1 * F3 * F, ib2_f + 1 * F3, xbuf, N);
    { bf16* tm = muin; muin = muout; muout = tm; }
    // ---- t = 1 ----
    edge_gather_d<0><<<N, 128, 0, stream>>>(muin, xbuf, phifc2, dir2,
                                            fWTf + (size_t)1 * F3 * KP, offs, dqb, dmub, N);
    mix8<0, 0><<<grid8, 256, 0, stream>>>(q, dqb, muin, dmub, muout,
                                          mWmixT + (size_t)1 * 2 * F * F,
                                          mW1T + (size_t)1 * F * 2 * F, mb1_f + 1 * F,
                                          mW2T + (size_t)1 * F3 * F, mb2_f + 1 * F3,
                                          nullptr, flag, N);
    atom_x_mfma<<<grid32, 256, 0, stream>>>(q, iW1T + (size_t)2 * F * F, ib1_f + 2 * F,
                                            iW2T + (size_t)2 * F3 * F, ib2_f + 2 * F3, xbuf, N);
    { bf16* tm = muin; muin = muout; muout = tm; }
    // ---- t = 2: final update straight to d_out ----
    edge_gather_d<0><<<N, 128, 0, stream>>>(muin, xbuf, phifc2, dir2,
                                            fWTf + (size_t)2 * F3 * KP, offs, dqb, dmub, N);
    mix8<0, 1><<<grid8, 256, 0, stream>>>(q, dqb, muin, dmub, muout,
                                          mWmixT + (size_t)2 * 2 * F * F,
                                          mW1T + (size_t)2 * F * 2 * F, mb1_f + 2 * F,
                                          mW2T + (size_t)2 * F3 * F, mb2_f + 2 * F3,
                                          d_out, flag, N);
}

// Round 10
// 751.466 us; speedup vs baseline: 1.1557x; 1.1557x over previous
//
#include <hip/hip_runtime.h>
#include <hip/hip_bf16.h>

#define F 128
#define F3 384
#define NRBF 20
#define NITER 3
#define KP 24   // padded filter K: 0..19 phi*fc, 20 fc (bias slot), 21..23 zero

typedef __hip_bfloat16 bf16;
typedef __bf16 bfrag __attribute__((ext_vector_type(8)));
typedef float f32x4 __attribute__((ext_vector_type(4)));

__device__ __forceinline__ float b2f(bf16 v) { return __bfloat162float(v); }
__device__ __forceinline__ bf16 f2b(float v) { return __float2bfloat16(v); }
__device__ __forceinline__ bfrag ldb(const bf16* p) { return *(const bfrag*)p; }
__device__ __forceinline__ bfrag ldsb(const __bf16* p) { return *(const bfrag*)p; }
__device__ __forceinline__ bfrag cvtf(const float* p) {
    bfrag r;
#pragma unroll
    for (int j = 0; j < 8; ++j) r[j] = (__bf16)p[j];
    return r;
}

// ---------------- dtype detection: bf16 (flag=0) vs f32 (flag=1) ----------------
__global__ void detect_kernel(const unsigned short* __restrict__ raw, int n_u16,
                              int* __restrict__ flag) {
    int i = blockIdx.x * blockDim.x + threadIdx.x;
    int bad = 0;
    for (int k = i; k < n_u16; k += blockDim.x * gridDim.x) {
        unsigned e = (raw[k] >> 7) & 0xFFu;
        if (e >= 140u) bad = 1;
    }
    if (bad) atomicOr(flag, 1);
}

// ---------------- fused param convert: 13 arrays in one launch ----------------
struct CvtArgs {
    const void* src[13];
    float* dst[13];
    int end[14];
};
__global__ void cvt_all_kernel(CvtArgs a, const int* __restrict__ flag, int total) {
    int idx = blockIdx.x * blockDim.x + threadIdx.x;
    if (idx >= total) return;
    int s = 0;
    while (idx >= a.end[s + 1]) ++s;
    int local = idx - a.end[s];
    float v = (*flag) ? ((const float*)a.src[s])[local]
                      : b2f(((const bf16*)a.src[s])[local]);
    a.dst[s][local] = v;
}

// ---------------- fused transpose: 5 weight tensors, f32[NITER][K][Nn]->bf16[NITER][Nn][K] ----
struct TpArgs {
    const float* src[5];
    bf16* dst[5];
    int K[5];
    int Nn[5];
    int end[6];
};
__global__ void tpose_all_kernel(TpArgs a, int total) {
    int idx = blockIdx.x * blockDim.x + threadIdx.x;
    if (idx >= total) return;
    int s = 0;
    while (idx >= a.end[s + 1]) ++s;
    int local = idx - a.end[s];
    int K = a.K[s], Nn = a.Nn[s], slice = K * Nn;
    int t = local / slice, j = local - t * slice;
    int n = j / K, k = j - n * K;
    a.dst[s][local] = f2b(a.src[s][t * slice + k * Nn + n]);
}

// ---------------- fWTf: f32 [NITER][384][24], k=0..19 fW, k=20 fb, rest 0 ----------------
__global__ void fwt_kernel(const float* __restrict__ fW, const float* __restrict__ fb,
                           float* __restrict__ dst, int total) {
    int idx = blockIdx.x * blockDim.x + threadIdx.x;
    if (idx >= total) return;
    int k = idx % KP, rest = idx / KP;
    int n = rest % F3, t = rest / F3;
    float v = (k < NRBF) ? fW[k * (F3 * NITER) + t * F3 + n]
                         : (k == NRBF ? fb[t * F3 + n] : 0.0f);
    dst[idx] = v;
}

// ---------------- geometry -> CSR-slot-ordered edge data ----------------
// dir2[l] = {dx, dy, dz, bitcast(j)}; phifc2 stored BF16 (halves the phi stream)
__global__ void geom_kernel(const float* __restrict__ pos, const int* __restrict__ ii,
                            const int* __restrict__ jj, const int* __restrict__ rank,
                            bf16* __restrict__ phifc2, float* __restrict__ dir2, int E) {
    int e = blockIdx.x * blockDim.x + threadIdx.x;
    if (e >= E) return;
    int i = ii[e], j = jj[e], l = rank[e];
    float r[3];
#pragma unroll
    for (int d = 0; d < 3; ++d) {
        float v = pos[j * 3 + d] - pos[i * 3 + d];
        if (fabsf(v) < 1e-6f) v = 1e-6f;
        r[d] = v;
    }
    float dd = sqrtf(r[0] * r[0] + r[1] * r[1] + r[2] * r[2]);
    float inv = 1.0f / dd;
#pragma unroll
    for (int d = 0; d < 3; ++d) dir2[(size_t)l * 4 + d] = r[d] * inv;
    dir2[(size_t)l * 4 + 3] = __int_as_float(j);
    const float CUT = 5.0f;
    const float PI = 3.14159265358979323846f;
    float fc = (dd < CUT) ? 0.5f * (cosf(PI * dd / CUT) + 1.0f) : 0.0f;
    const float width = CUT / (NRBF - 1);
    const float coeff = -0.5f / (width * width);
    bf16* pr = phifc2 + (size_t)l * KP;
#pragma unroll
    for (int k = 0; k < NRBF; ++k) {
        float diff = dd - (float)k * width;
        pr[k] = f2b(expf(coeff * diff * diff) * fc);
    }
    pr[NRBF] = f2b(fc);
    pr[NRBF + 1] = f2b(0.0f);
    pr[NRBF + 2] = f2b(0.0f);
    pr[NRBF + 3] = f2b(0.0f);
}

// ---------------- initial q from embedding ----------------
__global__ void embed_kernel(const int* __restrict__ z, const float* __restrict__ emb,
                             float* __restrict__ q, int N) {
    int idx = blockIdx.x * blockDim.x + threadIdx.x;
    if (idx >= N * F) return;
    int n = idx >> 7, f = idx & 127;
    q[idx] = emb[z[n] * F + f];
}

// ---------------- CSR build ----------------
__global__ void count_kernel(const int* __restrict__ ii, int* __restrict__ counts, int E) {
    int e = blockIdx.x * blockDim.x + threadIdx.x;
    if (e < E) atomicAdd(&counts[ii[e]], 1);
}

__global__ void scan_kernel(const int* __restrict__ counts, int* __restrict__ offs, int N) {
    __shared__ int cum[1024];
    int t = threadIdx.x;
    int chunk = (N + 1023) >> 10;
    int b = t * chunk;
    int e = b + chunk; if (e > N) e = N;
    int s = 0;
    for (int a = b; a < e; ++a) s += counts[a];
    cum[t] = s;
    __syncthreads();
    for (int o = 1; o < 1024; o <<= 1) {
        int u = (t >= o) ? cum[t - o] : 0;
        __syncthreads();
        cum[t] += u;
        __syncthreads();
    }
    int run = cum[t] - s;
    for (int a = b; a < e; ++a) { offs[a] = run; run += counts[a]; }
    if (t == 1023) offs[N] = cum[1023];
}

__global__ void fill_kernel(const int* __restrict__ ii, const int* __restrict__ offs,
                            int* __restrict__ cursor, int* __restrict__ rank, int E) {
    int e = blockIdx.x * blockDim.x + threadIdx.x;
    if (e >= E) return;
    int i = ii[e];
    int p = atomicAdd(&cursor[i], 1);
    rank[e] = offs[i] + p;
}

// ---------------- atom_x via MFMA: X = silu(Q@W1+b1)@W2+b2, 32 atoms/block ----------------
// The empirically-proven fast shape (~15us, ~2.1 TB/s effective): 2 phases, 8.7KB LDS.
__global__ __launch_bounds__(256) void atom_x_mfma(
    const float* __restrict__ q, const bf16* __restrict__ W1T, const float* __restrict__ b1,
    const bf16* __restrict__ W2T, const float* __restrict__ b2, bf16* __restrict__ x, int N) {
    __shared__ __bf16 H[32][136];
    int tid = threadIdx.x;
    int w = tid >> 6, l = tid & 63;
    int lm = l & 15, q4 = l >> 4;
    int i0 = blockIdx.x * 32;
    f32x4 acc[2][2] = {};
    int r0 = min(i0 + lm, N - 1);
    int r1 = min(i0 + 16 + lm, N - 1);
    for (int kt = 0; kt < 4; ++kt) {
        int ko = kt * 32 + q4 * 8;
        bfrag a0 = cvtf(q + (size_t)r0 * F + ko);
        bfrag a1 = cvtf(q + (size_t)r1 * F + ko);
        bfrag b0 = ldb(W1T + (size_t)(w * 32 + lm) * F + ko);
        bfrag b1f = ldb(W1T + (size_t)(w * 32 + 16 + lm) * F + ko);
        acc[0][0] = __builtin_amdgcn_mfma_f32_16x16x32_bf16(a0, b0, acc[0][0], 0, 0, 0);
        acc[1][0] = __builtin_amdgcn_mfma_f32_16x16x32_bf16(a1, b0, acc[1][0], 0, 0, 0);
        acc[0][1] = __builtin_amdgcn_mfma_f32_16x16x32_bf16(a0, b1f, acc[0][1], 0, 0, 0);
        acc[1][1] = __builtin_amdgcn_mfma_f32_16x16x32_bf16(a1, b1f, acc[1][1], 0, 0, 0);
    }
#pragma unroll
    for (int nt = 0; nt < 2; ++nt) {
        int col = w * 32 + nt * 16 + lm;
        float bb = b1[col];
#pragma unroll
        for (int mt = 0; mt < 2; ++mt)
#pragma unroll
            for (int r = 0; r < 4; ++r) {
                float v = acc[mt][nt][r] + bb;
                H[mt * 16 + q4 * 4 + r][col] = (__bf16)(v / (1.0f + expf(-v)));
            }
    }
    __syncthreads();
#pragma unroll
    for (int j = 0; j < 6; ++j) {
        int n0 = w * 96 + j * 16;
        f32x4 c0 = {}, c1 = {};
        const bf16* bp = W2T + (size_t)(n0 + lm) * F;
        for (int kt = 0; kt < 4; ++kt) {
            int ko = kt * 32 + q4 * 8;
            bfrag a0 = ldsb(&H[lm][ko]);
            bfrag a1 = ldsb(&H[16 + lm][ko]);
            bfrag bf = ldb(bp + ko);
            c0 = __builtin_amdgcn_mfma_f32_16x16x32_bf16(a0, bf, c0, 0, 0, 0);
            c1 = __builtin_amdgcn_mfma_f32_16x16x32_bf16(a1, bf, c1, 0, 0, 0);
        }
        int col = n0 + lm;
        float bb = b2[col];
#pragma unroll
        for (int r = 0; r < 4; ++r) {
            int row0 = i0 + q4 * 4 + r;
            int row1 = row0 + 16;
            if (row0 < N) x[(size_t)row0 * F3 + col] = f2b(c0[r] + bb);
            if (row1 < N) x[(size_t)row1 * F3 + col] = f2b(c1[r] + bb);
        }
    }
}

// ---------------- edge gather v5: delta outputs, bf16 phi + bf16 dq ----------------
// Model (6 data points): dur ~= (FETCH+WRITE) / ~1.7 TB/s.
template<int T0>
__global__ __launch_bounds__(128, 2) void edge_gather_d(
    const bf16* __restrict__ mu_in, const bf16* __restrict__ x,
    const bf16* __restrict__ phifc2, const float* __restrict__ dir2,
    const float* __restrict__ fWTf, const int* __restrict__ offs,
    bf16* __restrict__ dq, bf16* __restrict__ dmu, int N) {
    int i = blockIdx.x;
    int f = threadIdx.x;
    float w0[21], w1[21], w2[21];
    {
        const f32x4* p0 = (const f32x4*)(fWTf + (size_t)f * KP);
        const f32x4* p1 = (const f32x4*)(fWTf + (size_t)(f + 128) * KP);
#pragma unroll
        for (int k = 0; k < 6; ++k) {
            f32x4 t0 = p0[k], t1 = p1[k];
#pragma unroll
            for (int r = 0; r < 4; ++r) {
                int kk = k * 4 + r;
                if (kk < 21) { w0[kk] = t0[r]; w1[kk] = t1[r]; }
            }
        }
        if constexpr (!T0) {
            const f32x4* p2 = (const f32x4*)(fWTf + (size_t)(f + 256) * KP);
#pragma unroll
            for (int k = 0; k < 6; ++k) {
                f32x4 t2 = p2[k];
#pragma unroll
                for (int r = 0; r < 4; ++r) {
                    int kk = k * 4 + r;
                    if (kk < 21) w2[kk] = t2[r];
                }
            }
        }
    }
    // pin: value becomes opaque to the compiler -> cannot rematerialize the load
#pragma unroll
    for (int k = 0; k < 21; ++k) {
        asm volatile("" : "+v"(w0[k]), "+v"(w1[k]));
        if constexpr (!T0) asm volatile("" : "+v"(w2[k]));
    }
    int beg = offs[i], end = offs[i + 1];
    float accq = 0.0f, am0 = 0.0f, am1 = 0.0f, am2 = 0.0f;
    for (int l = beg; l < end; ++l) {
        const bfrag* pb = (const bfrag*)(phifc2 + (size_t)l * KP);
        bfrag p0 = __builtin_nontemporal_load(pb);
        bfrag p1 = __builtin_nontemporal_load(pb + 1);
        bfrag p2 = __builtin_nontemporal_load(pb + 2);
        float ph[21];
#pragma unroll
        for (int k = 0; k < 8; ++k) ph[k] = (float)p0[k];
#pragma unroll
        for (int k = 0; k < 8; ++k) ph[8 + k] = (float)p1[k];
#pragma unroll
        for (int k = 0; k < 5; ++k) ph[16 + k] = (float)p2[k];
        float fl0 = 0.0f, fl1 = 0.0f, fl2 = 0.0f;
#pragma unroll
        for (int k = 0; k < 21; ++k) {
            fl0 += ph[k] * w0[k];
            fl1 += ph[k] * w1[k];
            if constexpr (!T0) fl2 += ph[k] * w2[k];
        }
        f32x4 dv = __builtin_nontemporal_load((const f32x4*)(dir2 + (size_t)l * 4));
        int j = __float_as_int(dv[3]);
        const bf16* xj = x + (size_t)j * F3;
        float dqv = fl0 * b2f(xj[f]);
        float dR = fl1 * b2f(xj[f + 128]);
        accq += dqv;
        if constexpr (!T0) {
            float dM = fl2 * b2f(xj[f + 256]);
            const bf16* muj = mu_in + (size_t)j * F3;
            am0 += dR * dv[0] + dM * b2f(muj[f]);
            am1 += dR * dv[1] + dM * b2f(muj[f + 128]);
            am2 += dR * dv[2] + dM * b2f(muj[f + 256]);
        } else {
            am0 += dR * dv[0];
            am1 += dR * dv[1];
            am2 += dR * dv[2];
        }
    }
    dq[(size_t)i * F + f] = f2b(accq);
    size_t mb = (size_t)i * F3 + f;
    dmu[mb]       = f2b(am0);
    dmu[mb + 128] = f2b(am1);
    dmu[mb + 256] = f2b(am2);
}

// ---------------- mixv: Wmix GEMM -> Vn, s, W (slim 2-phase, 16 atoms/block) ----------------
// R8-proven shape (~2 TB/s effective). R10: S stream bf16 (-12.8 MB/iter round trip).
template<int T0>
__global__ __launch_bounds__(256) void mixv_mfma(
    const bf16* __restrict__ mu_in, const bf16* __restrict__ dmu,
    const bf16* __restrict__ WmixT,
    bf16* __restrict__ Vn_g, bf16* __restrict__ S_g, bf16* __restrict__ Wg, int N) {
    __shared__ __bf16 VV[48][131];
    __shared__ __bf16 WW[48][130];
    int tid = threadIdx.x;
    int w = tid >> 6, l = tid & 63;
    int lm = l & 15, q4 = l >> 4;
    int i0 = blockIdx.x * 16;
    int rowsM = N * 3;
    {
        f32x4 acc[3][4] = {};
        int mr[3];
#pragma unroll
        for (int mt = 0; mt < 3; ++mt) mr[mt] = min(i0 * 3 + mt * 16 + lm, rowsM - 1);
        for (int kt = 0; kt < 4; ++kt) {
            int ko = kt * 32 + q4 * 8;
            bfrag a[3], b[4];
#pragma unroll
            for (int mt = 0; mt < 3; ++mt) {
                bfrag d = ldb(dmu + (size_t)mr[mt] * F + ko);
                if constexpr (T0) {
                    a[mt] = d;
                } else {
                    bfrag u = ldb(mu_in + (size_t)mr[mt] * F + ko);
#pragma unroll
                    for (int jj = 0; jj < 8; ++jj)
                        a[mt][jj] = (__bf16)((float)u[jj] + (float)d[jj]);
                }
            }
#pragma unroll
            for (int nt = 0; nt < 4; ++nt)
                b[nt] = ldb(WmixT + (size_t)(w * 64 + nt * 16 + lm) * F + ko);
#pragma unroll
            for (int mt = 0; mt < 3; ++mt)
#pragma unroll
                for (int nt = 0; nt < 4; ++nt)
                    acc[mt][nt] = __builtin_amdgcn_mfma_f32_16x16x32_bf16(a[mt], b[nt], acc[mt][nt], 0, 0, 0);
        }
#pragma unroll
        for (int mt = 0; mt < 3; ++mt)
#pragma unroll
            for (int nt = 0; nt < 4; ++nt) {
                int col = w * 64 + nt * 16 + lm;   // uniform per (w,nt): col<128 iff w<2
#pragma unroll
                for (int r = 0; r < 4; ++r) {
                    int row = mt * 16 + q4 * 4 + r;
                    if (col < 128) VV[row][col] = (__bf16)acc[mt][nt][r];
                    else           WW[row][col - 128] = (__bf16)acc[mt][nt][r];
                }
            }
    }
    __syncthreads();
    for (int idx = tid; idx < 16 * F; idx += 256) {
        int a = idx >> 7, f = idx & 127;
        int i = i0 + a;
        if (i >= N) continue;
        float v0 = (float)VV[a * 3 + 0][f], w0 = (float)WW[a * 3 + 0][f];
        float v1 = (float)VV[a * 3 + 1][f], w1 = (float)WW[a * 3 + 1][f];
        float v2 = (float)VV[a * 3 + 2][f], w2 = (float)WW[a * 3 + 2][f];
        size_t qb = (size_t)i * F + f;
        Vn_g[qb] = f2b(sqrtf(v0 * v0 + v1 * v1 + v2 * v2 + 1e-8f));
        S_g[qb] = f2b(v0 * w0 + v1 * w1 + v2 * w2);
        size_t mb = (size_t)i * F3 + f;
        Wg[mb]       = f2b(w0);
        Wg[mb + 128] = f2b(w1);
        Wg[mb + 256] = f2b(w2);
    }
}

// ---------------- ctx_final: ctx MLP + final update, 32 atoms/block ----------------
// Phases: A) CT = [q+dq, Vn]  B) W1 GEMM (K=256) -> silu  C) W2 GEMM -> Y (LDS,
// aliased over CT)  D) elementwise final: q/mu update from Y, W, s, deltas.
// LDS 33.8KB -> 4 blocks/CU; 3 barriers.
template<int T0, int OUT>
__global__ __launch_bounds__(256) void ctx_final(
    float* __restrict__ q, const bf16* __restrict__ dqb,
    const bf16* __restrict__ mu_in, const bf16* __restrict__ dmu,
    const bf16* __restrict__ Vn_g, const bf16* __restrict__ S_g, const bf16* __restrict__ Wg,
    bf16* __restrict__ mu_out,
    const bf16* __restrict__ W1T, const float* __restrict__ b1,
    const bf16* __restrict__ W2T, const float* __restrict__ b2,
    void* __restrict__ outp, const int* __restrict__ flag, int N) {
    // [0, 25088): union{ CT[32][264] (A->B), Y[32][392] (C->D) }
    // [25088, 33792): HM[32][136] (B->C)
    __shared__ __align__(16) char smem[33792];
    __bf16 (*CT)[264] = (__bf16(*)[264])(smem);
    __bf16 (*Y)[392]  = (__bf16(*)[392])(smem);
    __bf16 (*HM)[136] = (__bf16(*)[136])(smem + 25088);
    int tid = threadIdx.x;
    int w = tid >> 6, l = tid & 63;
    int lm = l & 15, q4 = l >> 4;
    int i0 = blockIdx.x * 32;
    // A: build context rows
    for (int idx = tid; idx < 32 * F; idx += 256) {
        int a = idx >> 7, f = idx & 127;
        int i = min(i0 + a, N - 1);
        size_t qb = (size_t)i * F + f;
        float qe = q[qb] + b2f(dqb[qb]);
        CT[a][f] = (__bf16)qe;
        CT[a][F + f] = (__bf16)b2f(Vn_g[qb]);
    }
    __syncthreads();
    // B: HM = silu(CT @ W1 + b1), K=256
    {
        f32x4 c0[2] = {}, c1[2] = {};
        for (int kt = 0; kt < 8; ++kt) {
            int ko = kt * 32 + q4 * 8;
            bfrag a0 = ldsb(&CT[lm][ko]);
            bfrag a1 = ldsb(&CT[16 + lm][ko]);
#pragma unroll
            for (int nt = 0; nt < 2; ++nt) {
                bfrag b = ldb(W1T + (size_t)(w * 32 + nt * 16 + lm) * 256 + ko);
                c0[nt] = __builtin_amdgcn_mfma_f32_16x16x32_bf16(a0, b, c0[nt], 0, 0, 0);
                c1[nt] = __builtin_amdgcn_mfma_f32_16x16x32_bf16(a1, b, c1[nt], 0, 0, 0);
            }
        }
#pragma unroll
        for (int nt = 0; nt < 2; ++nt) {
            int col = w * 32 + nt * 16 + lm;
            float bb = b1[col];
#pragma unroll
            for (int r = 0; r < 4; ++r) {
                float v0 = c0[nt][r] + bb;
                float v1 = c1[nt][r] + bb;
                HM[q4 * 4 + r][col] = (__bf16)(v0 / (1.0f + expf(-v0)));
                HM[16 + q4 * 4 + r][col] = (__bf16)(v1 / (1.0f + expf(-v1)));
            }
        }
    }
    __syncthreads();   // CT dead; Y may reuse its storage
    // C: Y = HM @ W2 + b2
#pragma unroll
    for (int j = 0; j < 6; ++j) {
        int n0 = w * 96 + j * 16;
        f32x4 c0 = {}, c1 = {};
        const bf16* bp = W2T + (size_t)(n0 + lm) * F;
        for (int kt = 0; kt < 4; ++kt) {
            int ko = kt * 32 + q4 * 8;
            bfrag a0 = ldsb(&HM[lm][ko]);
            bfrag a1 = ldsb(&HM[16 + lm][ko]);
            bfrag b = ldb(bp + ko);
            c0 = __builtin_amdgcn_mfma_f32_16x16x32_bf16(a0, b, c0, 0, 0, 0);
            c1 = __builtin_amdgcn_mfma_f32_16x16x32_bf16(a1, b, c1, 0, 0, 0);
        }
        int col = n0 + lm;
        float bb = b2[col];
#pragma unroll
        for (int r = 0; r < 4; ++r) {
            Y[q4 * 4 + r][col] = (__bf16)(c0[r] + bb);
            Y[16 + q4 * 4 + r][col] = (__bf16)(c1[r] + bb);
        }
    }
    __syncthreads();
    // D: elementwise final update
    int nq = N * F;
    for (int idx = tid; idx < 32 * F; idx += 256) {
        int a = idx >> 7, f = idx & 127;
        int i = i0 + a;
        if (i >= N) continue;
        size_t qb = (size_t)i * F + f;
        size_t mb = (size_t)i * F3 + f;
        float yq = (float)Y[a][f], ym = (float)Y[a][F + f], ys = (float)Y[a][2 * F + f];
        float s = b2f(S_g[qb]);
        float W0 = b2f(Wg[mb]);
        float W1v = b2f(Wg[mb + 128]);
        float W2v = b2f(Wg[mb + 256]);
        float qv = q[qb] + b2f(dqb[qb]) + yq + ys * s;
        float m0 = b2f(dmu[mb]);
        float m1 = b2f(dmu[mb + 128]);
        float m2 = b2f(dmu[mb + 256]);
        if constexpr (!T0) {
            m0 += b2f(mu_in[mb]);
            m1 += b2f(mu_in[mb + 128]);
            m2 += b2f(mu_in[mb + 256]);
        }
        m0 += ym * W0;
        m1 += ym * W1v;
        m2 += ym * W2v;
        if constexpr (OUT) {
            if (*flag) {
                float* of = (float*)outp;
                of[qb] = qv;
                of[nq + mb] = m0;
                of[nq + mb + 128] = m1;
                of[nq + mb + 256] = m2;
            } else {
                bf16* ob = (bf16*)outp;
                ob[qb] = f2b(qv);
                ob[nq + mb] = f2b(m0);
                ob[nq + mb + 128] = f2b(m1);
                ob[nq + mb + 256] = f2b(m2);
            }
        } else {
            q[qb] = qv;
            mu_out[mb]       = f2b(m0);
            mu_out[mb + 128] = f2b(m1);
            mu_out[mb + 256] = f2b(m2);
        }
    }
}

extern "C" void kernel_launch(void* const* d_in, const int* in_sizes, int n_in,
                              void* d_out, int out_size, void* d_ws, size_t ws_size,
                              hipStream_t stream) {
    const int* z = (const int*)d_in[0];
    const int* idx_i = (const int*)d_in[2];
    const int* idx_j = (const int*)d_in[3];

    int N = in_sizes[0];
    int E = in_sizes[2];

    char* base = (char*)d_ws;
    size_t off = 0;
    auto alloc = [&](size_t bytes) -> void* {
        void* p = base + off;
        off += (bytes + 255) & ~(size_t)255;
        return p;
    };

    int* flag = (int*)alloc(4);
    float* pos_f = (float*)alloc((size_t)in_sizes[1] * 4);
    float* emb_f = (float*)alloc((size_t)in_sizes[4] * 4);
    float* fW_f = (float*)alloc((size_t)in_sizes[5] * 4);
    float* fb_f = (float*)alloc((size_t)in_sizes[6] * 4);
    float* iW1_f = (float*)alloc((size_t)in_sizes[7] * 4);
    float* ib1_f = (float*)alloc((size_t)in_sizes[8] * 4);
    float* iW2_f = (float*)alloc((size_t)in_sizes[9] * 4);
    float* ib2_f = (float*)alloc((size_t)in_sizes[10] * 4);
    float* mWmix_f = (float*)alloc((size_t)in_sizes[11] * 4);
    float* mW1_f = (float*)alloc((size_t)in_sizes[12] * 4);
    float* mb1_f = (float*)alloc((size_t)in_sizes[13] * 4);
    float* mW2_f = (float*)alloc((size_t)in_sizes[14] * 4);
    float* mb2_f = (float*)alloc((size_t)in_sizes[15] * 4);
    bf16* iW1T = (bf16*)alloc((size_t)NITER * F * F * 2);
    bf16* iW2T = (bf16*)alloc((size_t)NITER * F3 * F * 2);
    bf16* mWmixT = (bf16*)alloc((size_t)NITER * 2 * F * F * 2);
    bf16* mW1T = (bf16*)alloc((size_t)NITER * F * 2 * F * 2);
    bf16* mW2T = (bf16*)alloc((size_t)NITER * F3 * F * 2);
    float* fWTf = (float*)alloc((size_t)NITER * F3 * KP * 4);
    float* q = (float*)alloc((size_t)N * F * 4);
    bf16* dqb = (bf16*)alloc((size_t)N * F * 2);
    bf16* mua = (bf16*)alloc((size_t)N * F3 * 2);
    bf16* mub = (bf16*)alloc((size_t)N * F3 * 2);
    bf16* dmub = (bf16*)alloc((size_t)N * F3 * 2);
    bf16* xbuf = (bf16*)alloc((size_t)N * F3 * 2);
    bf16* Vn_g = (bf16*)alloc((size_t)N * F * 2);
    bf16* S_g = (bf16*)alloc((size_t)N * F * 2);
    bf16* Wg = (bf16*)alloc((size_t)N * F3 * 2);
    bf16* phifc2 = (bf16*)alloc((size_t)(E + 16) * KP * 2);
    float* dir2 = (float*)alloc((size_t)(E + 16) * 4 * 4);
    int* rank = (int*)alloc((size_t)E * 4);
    int* counts = (int*)alloc((size_t)N * 4);
    int* offs = (int*)alloc((size_t)(N + 1) * 4);

    hipMemsetAsync(flag, 0, 4, stream);
    detect_kernel<<<64, 256, 0, stream>>>((const unsigned short*)d_in[1], in_sizes[1], flag);

    {
        CvtArgs a;
        const int srcIdx[13] = {1, 4, 5, 6, 7, 8, 9, 10, 11, 12, 13, 14, 15};
        float* dsts[13] = {pos_f, emb_f, fW_f, fb_f, iW1_f, ib1_f, iW2_f, ib2_f,
                           mWmix_f, mW1_f, mb1_f, mW2_f, mb2_f};
        int cum = 0;
        a.end[0] = 0;
        for (int s = 0; s < 13; ++s) {
            a.src[s] = d_in[srcIdx[s]];
            a.dst[s] = dsts[s];
            cum += in_sizes[srcIdx[s]];
            a.end[s + 1] = cum;
        }
        cvt_all_kernel<<<(cum + 255) / 256, 256, 0, stream>>>(a, flag, cum);
    }

    {
        TpArgs a;
        const float* srcs[5] = {iW1_f, iW2_f, mWmix_f, mW1_f, mW2_f};
        bf16* dsts[5] = {iW1T, iW2T, mWmixT, mW1T, mW2T};
        int Ks[5] = {F, F, F, 2 * F, F};
        int Nns[5] = {F, F3, 2 * F, F, F3};
        int cum = 0;
        a.end[0] = 0;
        for (int s = 0; s < 5; ++s) {
            a.src[s] = srcs[s];
            a.dst[s] = dsts[s];
            a.K[s] = Ks[s];
            a.Nn[s] = Nns[s];
            cum += NITER * Ks[s] * Nns[s];
            a.end[s + 1] = cum;
        }
        tpose_all_kernel<<<(cum + 255) / 256, 256, 0, stream>>>(a, cum);
    }
    {
        int total = NITER * F3 * KP;
        fwt_kernel<<<(total + 255) / 256, 256, 0, stream>>>(fW_f, fb_f, fWTf, total);
    }

    // CSR build (rank needed by geom)
    hipMemsetAsync(counts, 0, (size_t)N * 4, stream);
    count_kernel<<<(E + 255) / 256, 256, 0, stream>>>(idx_i, counts, E);
    scan_kernel<<<1, 1024, 0, stream>>>(counts, offs, N);
    hipMemsetAsync(counts, 0, (size_t)N * 4, stream);
    fill_kernel<<<(E + 255) / 256, 256, 0, stream>>>(idx_i, offs, counts, rank, E);

    geom_kernel<<<(E + 255) / 256, 256, 0, stream>>>(pos_f, idx_i, idx_j, rank,
                                                     phifc2, dir2, E);
    embed_kernel<<<(N * F + 255) / 256, 256, 0, stream>>>(z, emb_f, q, N);
    // mua never read before first full write (t=0 path uses deltas only)

    int grid16 = (N + 15) / 16;
    int grid32 = (N + 31) / 32;
    bf16* muin = mua;
    bf16* muout = mub;
    // x for t=0 from initial q
    atom_x_mfma<<<grid32, 256, 0, stream>>>(q, iW1T, ib1_f, iW2T, ib2_f, xbuf, N);
    // ---- t = 0 ----
    edge_gather_d<1><<<N, 128, 0, stream>>>(muin, xbuf, phifc2, dir2,
                                            fWTf, offs, dqb, dmub, N);
    mixv_mfma<1><<<grid16, 256, 0, stream>>>(muin, dmub, mWmixT, Vn_g, S_g, Wg, N);
    ctx_final<1, 0><<<grid32, 256, 0, stream>>>(q, dqb, muin, dmub, Vn_g, S_g, Wg, muout,
                                                mW1T, mb1_f, mW2T, mb2_f,
                                                nullptr, flag, N);
    atom_x_mfma<<<grid32, 256, 0, stream>>>(q, iW1T + (size_t)1 * F * F, ib1_f + 1 * F,
                                            iW2T + (size_t)1 * F3 * F, ib2_f + 1 * F3, xbuf, N);
    { bf16* tm = muin; muin = muout; muout = tm; }
    // ---- t = 1 ----
    edge_gather_d<0><<<N, 128, 0, stream>>>(muin, xbuf, phifc2, dir2,
                                            fWTf + (size_t)1 * F3 * KP, offs, dqb, dmub, N);
    mixv_mfma<0><<<grid16, 256, 0, stream>>>(muin, dmub, mWmixT + (size_t)1 * 2 * F * F,
                                             Vn_g, S_g, Wg, N);
    ctx_final<0, 0><<<grid32, 256, 0, stream>>>(q, dqb, muin, dmub, Vn_g, S_g, Wg, muout,
                                                mW1T + (size_t)1 * F * 2 * F, mb1_f + 1 * F,
                                                mW2T + (size_t)1 * F3 * F, mb2_f + 1 * F3,
                                                nullptr, flag, N);
    atom_x_mfma<<<grid32, 256, 0, stream>>>(q, iW1T + (size_t)2 * F * F, ib1_f + 2 * F,
                                            iW2T + (size_t)2 * F3 * F, ib2_f + 2 * F3, xbuf, N);
    { bf16* tm = muin; muin = muout; muout = tm; }
    // ---- t = 2: final update straight to d_out ----
    edge_gather_d<0><<<N, 128, 0, stream>>>(muin, xbuf, phifc2, dir2,
                                            fWTf + (size_t)2 * F3 * KP, offs, dqb, dmub, N);
    mixv_mfma<0><<<grid16, 256, 0, stream>>>(muin, dmub, mWmixT + (size_t)2 * 2 * F * F,
                                             Vn_g, S_g, Wg, N);
    ctx_final<0, 1><<<grid32, 256, 0, stream>>>(q, dqb, muin, dmub, Vn_g, S_g, Wg, muout,
                                                mW1T + (size_t)2 * F * 2 * F, mb1_f + 2 * F,
                                                mW2T + (size_t)2 * F3 * F, mb2_f + 2 * F3,
                                                d_out, flag, N);
}